// Round 8
// baseline (687.815 us; speedup 1.0000x reference)
//
#include <hip/hip_runtime.h>

#define BB 8
#define TT 16
#define CIN 32
#define HID 64
#define HH 64
#define WW 64
#define EPS 1e-3f
#define NEG_SLOPE 0.01f

typedef short s16x8 __attribute__((ext_vector_type(8)));
typedef _Float16 hx8 __attribute__((ext_vector_type(8)));
typedef float fx4 __attribute__((ext_vector_type(4)));

__device__ __forceinline__ float tanh_fast(float x) {
    x = fminf(fmaxf(x, -15.f), 15.f);
    float e = __expf(-2.f * x);
    return (1.f - e) / (1.f + e);
}

// x (NCHW fp32) -> xcl [b][t][y*64+x][32] f16
__global__ __launch_bounds__(256) void x2h(const float* __restrict__ x,
                                           _Float16* __restrict__ xcl) {
    __shared__ float s[32][65];
    int y = blockIdx.x, t = blockIdx.y, b = blockIdx.z;
    int tid = threadIdx.x;
    const float* src = x + (((size_t)(b * TT + t) * CIN) * HH + y) * WW;
#pragma unroll
    for (int k = 0; k < 8; ++k) {
        int idx = tid + k * 256;
        int c = idx >> 6, xx = idx & 63;
        s[c][xx] = src[(size_t)c * HH * WW + xx];
    }
    __syncthreads();
    int xx = tid >> 2, c0 = (tid & 3) * 8;
    _Float16 tmp[8];
#pragma unroll
    for (int j = 0; j < 8; ++j) tmp[j] = (_Float16)s[c0 + j][xx];
    _Float16* dst = xcl + (((size_t)(b * TT + t) * 4096) + y * 64 + xx) * 32 + c0;
    *(hx8*)dst = *(hx8*)tmp;
}

// w [256 oc][96 ch][3][3] fp32 -> wpk [tap(9)][kc(3)][kq(4)][n(256)][k7(8)] f16
__global__ __launch_bounds__(256) void pack_wh(const float* __restrict__ w,
                                               _Float16* __restrict__ wpk) {
    int idx = blockIdx.x * 256 + threadIdx.x;
    if (idx >= 256 * 864) return;
    int k7 = idx & 7;
    int j = idx >> 3;
    int n = j & 255;
    int kk = j >> 8;            // tap*12 + kc*4 + kq
    int tap = kk / 12;
    int r12 = kk % 12;
    int ks = (r12 >> 2) * 32 + (r12 & 3) * 8 + k7;
    int gate = (n >> 4) & 3;
    int hid  = (n >> 6) * 16 + (n & 15);
    int oc   = gate * 64 + hid;
    wpk[idx] = (_Float16)w[((size_t)oc * 96 + ks) * 9 + tap];
}

// TWO timesteps per launch via halo fusion. grid (32 rb, 8 b) x 512 thr,
// 1 block/CU, dynamic LDS 137,280 B (opt-in; gfx950 allows 160 KB/wg).
// Block owns rows base=rb*2, base+1. Step t0: computes 4 rows [base-1,base+3)
// (1-row halo; redundant with neighbors, bitwise-identical). Step t0+1:
// computes the 2 interior rows from purely local data:
//   h(t0) handed via LDS tileB, c(t0) handed via registers (same lane owns
//   the pixel in both steps). No flags/fences; launch boundary is the sync.
// Wave (u=w>>2, w4=w&3): step t0 wave owns trows 2u..2u+1 (acc[8][4]);
// step t0+1 wave owns row base+u (acc2[4][4]). kq = intra-wave K-octet.
__global__ __launch_bounds__(512, 2) void lstm_pair(
    const _Float16* __restrict__ xcl,
    const _Float16* __restrict__ wpk,
    const float* __restrict__ bias,
    const _Float16* __restrict__ h_in,
    _Float16* __restrict__ h_out,
    const float* __restrict__ c_in,
    float* __restrict__ c_out,
    float* __restrict__ out,
    float* __restrict__ partial,
    int t0) {
    extern __shared__ __align__(16) unsigned short lds[];
    unsigned short* tA = lds;                 // 6*66*104 shorts (input tile t0)
    unsigned short* tB = lds + 6 * 66 * 104;  // 4*66*104 shorts (input tile t0+1)

    const int rb = blockIdx.x, b = blockIdx.y;
    const int base = rb * 2;
    const int tid = threadIdx.x;
    const int lane15 = tid & 15;
    const int kq = (tid >> 4) & 3;
    const int w = tid >> 6;
    const int w4 = w & 3;
    const int u = w >> 2;

    // ---- stage tileA: x(t0) ch 0..31, 6 rows [base-2, base+4) ----
    const short* xb_t = (const short*)xcl + (size_t)(b * TT + t0) * 4096 * 32;
    for (int i = tid; i < 6 * 66 * 4; i += 512) {
        int unit = i & 3, pix = i >> 2;
        int col = pix % 66, ra = pix / 66;
        int iy = base - 2 + ra, ix = col - 1;
        s16x8 v = (s16x8)0;
        if (iy >= 0 && iy < 64 && ix >= 0 && ix < 64)
            v = *(const s16x8*)(xb_t + ((size_t)iy * 64 + ix) * 32 + unit * 8);
        *(s16x8*)(tA + (ra * 66 + col) * 104 + unit * 8) = v;
    }
    // ---- stage tileA: h(t0-1) ch 32..95 ----
    if (t0 > 0) {
        for (int i = tid; i < 6 * 66 * 8; i += 512) {
            int unit = i & 7, pix = i >> 3;
            int col = pix % 66, ra = pix / 66;
            int iy = base - 2 + ra, ix = col - 1;
            s16x8 v = (s16x8)0;
            if (iy >= 0 && iy < 64 && ix >= 0 && ix < 64)
                v = *(const s16x8*)((const short*)h_in +
                                    ((size_t)(b * 64 + iy) * 64 + ix) * 64 + unit * 8);
            *(s16x8*)(tA + (ra * 66 + col) * 104 + 32 + unit * 8) = v;
        }
    }
    // ---- stage tileB: x(t0+1) ch 0..31, 4 rows [base-1, base+3) ----
    const short* xb_t1 = (const short*)xcl + (size_t)(b * TT + t0 + 1) * 4096 * 32;
    for (int i = tid; i < 4 * 66 * 4; i += 512) {
        int unit = i & 3, pix = i >> 2;
        int col = pix % 66, rw = pix / 66;
        int iy = base - 1 + rw, ix = col - 1;
        s16x8 v = (s16x8)0;
        if (iy >= 0 && iy < 64 && ix >= 0 && ix < 64)
            v = *(const s16x8*)(xb_t1 + ((size_t)iy * 64 + ix) * 32 + unit * 8);
        *(s16x8*)(tB + (rw * 66 + col) * 104 + unit * 8) = v;
    }
    // ---- zero tileB h-channels (epilogue-t overwrites valid pixels) ----
    for (int i = tid; i < 4 * 66 * 8; i += 512) {
        int unit = i & 7, pix = i >> 3;
        int col = pix % 66, rw = pix / 66;
        *(s16x8*)(tB + (rw * 66 + col) * 104 + 32 + unit * 8) = (s16x8)0;
    }
    __syncthreads();

    // ---- step t0 tap loop: acc[8][4], m-frag j: trow=2u+(j>>2), colq=j&3 ----
    fx4 acc[8][4];
#pragma unroll
    for (int j = 0; j < 8; ++j)
#pragma unroll
        for (int g = 0; g < 4; ++g) acc[j][g] = (fx4)0.f;

    const int nbase = 4 * w4 * 16 + lane15;

    if (t0 > 0) {
#pragma unroll 1
        for (int tap = 0; tap < 9; ++tap) {
            const int ky = tap / 3, kx = tap % 3;
            const _Float16* wp = wpk + ((size_t)(tap * 12 + kq) * 256 + nbase) * 8;
#pragma unroll
            for (int kc = 0; kc < 3; ++kc) {
                hx8 bf[4];
#pragma unroll
                for (int g = 0; g < 4; ++g)
                    bf[g] = *(const hx8*)(wp + (size_t)(kc * 4) * 256 * 8 + g * 16 * 8);
#pragma unroll
                for (int j = 0; j < 8; ++j) {
                    int ra = 2 * u + (j >> 2) + ky;
                    int ccol = (j & 3) * 16 + lane15 + kx;
                    hx8 af = *(const hx8*)(tA + (ra * 66 + ccol) * 104 + kc * 32 + kq * 8);
#pragma unroll
                    for (int g = 0; g < 4; ++g)
                        acc[j][g] = __builtin_amdgcn_mfma_f32_16x16x32_f16(af, bf[g], acc[j][g], 0, 0, 0);
                }
            }
        }
    } else {
#pragma unroll 1
        for (int tap = 0; tap < 9; ++tap) {
            const int ky = tap / 3, kx = tap % 3;
            const _Float16* wp = wpk + ((size_t)(tap * 12 + kq) * 256 + nbase) * 8;
            hx8 bf[4];
#pragma unroll
            for (int g = 0; g < 4; ++g)
                bf[g] = *(const hx8*)(wp + g * 16 * 8);
#pragma unroll
            for (int j = 0; j < 8; ++j) {
                int ra = 2 * u + (j >> 2) + ky;
                int ccol = (j & 3) * 16 + lane15 + kx;
                hx8 af = *(const hx8*)(tA + (ra * 66 + ccol) * 104 + kq * 8);
#pragma unroll
                for (int g = 0; g < 4; ++g)
                    acc[j][g] = __builtin_amdgcn_mfma_f32_16x16x32_f16(af, bf[g], acc[j][g], 0, 0, 0);
            }
        }
    }

    // ---- epilogue t0: gate math; h(t0)->tileB; interior c(t0)->registers ----
    const int hid = w4 * 16 + lane15;
    const float bi = bias[hid], bff = bias[64 + hid];
    const float bo = bias[128 + hid], bg = bias[192 + hid];
    fx4 creg[4];
    float osum = 0.f, osum2 = 0.f;
#pragma unroll
    for (int j = 0; j < 8; ++j) {
        int trow = 2 * u + (j >> 2), colq = j & 3;
        int oy = base - 1 + trow;
        bool exist = (oy >= 0 && oy < 64);
        bool interior = ((j >> 2) == 1 - u);
        int col = colq * 16 + kq * 4;
        float4 o4;
#pragma unroll
        for (int r4 = 0; r4 < 4; ++r4) {
            float ci = acc[j][0][r4] + bi;
            float cf = acc[j][1][r4] + bff;
            float co = acc[j][2][r4] + bo;
            float cg_ = acc[j][3][r4] + bg;
            size_t ca = ((size_t)(b * 64 + oy) * 64 + col + r4) * 64 + hid;
            float c_old = (t0 > 0 && exist) ? c_in[ca] : 0.f;
            float si = 1.f / (1.f + __expf(-ci));
            float sf = 1.f / (1.f + __expf(-cf));
            float so = 1.f / (1.f + __expf(-co));
            float c_new = sf * c_old + si * tanh_fast(cg_);
            float h = so * tanh_fast(c_new);
            if (exist)
                ((_Float16*)tB)[(trow * 66 + col + r4 + 1) * 104 + 32 + hid] = (_Float16)h;
            if (interior) {
                creg[colq][r4] = c_new;
                float ov = (h >= 0.f) ? h : NEG_SLOPE * h;
                (&o4.x)[r4] = ov;
                osum += ov;
                osum2 += ov * ov;
            }
        }
        if (interior)
            *(float4*)(out + (((size_t)(b * TT + t0) * 64 + hid) * 64 + oy) * 64 + col) = o4;
    }
    __syncthreads();

    // ---- step t0+1 tap loop: acc2[4][4], row base+u ----
    fx4 acc2[4][4];
#pragma unroll
    for (int j = 0; j < 4; ++j)
#pragma unroll
        for (int g = 0; g < 4; ++g) acc2[j][g] = (fx4)0.f;

#pragma unroll 1
    for (int tap = 0; tap < 9; ++tap) {
        const int ky = tap / 3, kx = tap % 3;
        const _Float16* wp = wpk + ((size_t)(tap * 12 + kq) * 256 + nbase) * 8;
#pragma unroll
        for (int kc = 0; kc < 3; ++kc) {
            hx8 bf[4];
#pragma unroll
            for (int g = 0; g < 4; ++g)
                bf[g] = *(const hx8*)(wp + (size_t)(kc * 4) * 256 * 8 + g * 16 * 8);
            int ra = u + ky;
#pragma unroll
            for (int j = 0; j < 4; ++j) {
                int ccol = j * 16 + lane15 + kx;
                hx8 af = *(const hx8*)(tB + (ra * 66 + ccol) * 104 + kc * 32 + kq * 8);
#pragma unroll
                for (int g = 0; g < 4; ++g)
                    acc2[j][g] = __builtin_amdgcn_mfma_f32_16x16x32_f16(af, bf[g], acc2[j][g], 0, 0, 0);
            }
        }
    }

    // ---- epilogue t0+1: c from registers; write h/c for next launch ----
    {
        int oy = base + u;
#pragma unroll
        for (int j = 0; j < 4; ++j) {
            int col = j * 16 + kq * 4;
            float4 o4;
#pragma unroll
            for (int r4 = 0; r4 < 4; ++r4) {
                float ci = acc2[j][0][r4] + bi;
                float cf = acc2[j][1][r4] + bff;
                float co = acc2[j][2][r4] + bo;
                float cg_ = acc2[j][3][r4] + bg;
                float c_old = creg[j][r4];
                float si = 1.f / (1.f + __expf(-ci));
                float sf = 1.f / (1.f + __expf(-cf));
                float so = 1.f / (1.f + __expf(-co));
                float c_new = sf * c_old + si * tanh_fast(cg_);
                float h = so * tanh_fast(c_new);
                size_t ca = ((size_t)(b * 64 + oy) * 64 + col + r4) * 64 + hid;
                if (t0 + 1 < TT - 1) {
                    c_out[ca] = c_new;
                    h_out[ca] = (_Float16)h;
                }
                float ov = (h >= 0.f) ? h : NEG_SLOPE * h;
                (&o4.x)[r4] = ov;
                osum += ov;
                osum2 += ov * ov;
            }
            *(float4*)(out + (((size_t)(b * TT + t0 + 1) * 64 + hid) * 64 + oy) * 64 + col) = o4;
        }
    }

    osum  += __shfl_xor(osum, 16);  osum  += __shfl_xor(osum, 32);
    osum2 += __shfl_xor(osum2, 16); osum2 += __shfl_xor(osum2, 32);
    if (kq == 0) {
        int slot = b * 64 + base + u;           // 512 slots
        if (t0 == 0) {
            partial[slot * 128 + hid] = osum;
            partial[slot * 128 + 64 + hid] = osum2;
        } else {
            partial[slot * 128 + hid] += osum;
            partial[slot * 128 + 64 + hid] += osum2;
        }
    }
}

__global__ __launch_bounds__(512) void finalize_stats(const float* __restrict__ partial,
                                                      float* __restrict__ stats,
                                                      const float* __restrict__ gamma,
                                                      const float* __restrict__ beta) {
    int idx = threadIdx.x & 127;
    int seg = threadIdx.x >> 7;       // 0..3, each sums 128 of 512 rows
    float s = 0.f;
    for (int k = seg * 128; k < seg * 128 + 128; ++k) s += partial[k * 128 + idx];
    __shared__ float red[4][128];
    red[seg][idx] = s;
    __syncthreads();
    if (threadIdx.x < 64) {
        int hid = threadIdx.x;
        const float n = (float)((size_t)BB * TT * HH * WW);
        float mean = (red[0][hid] + red[1][hid] + red[2][hid] + red[3][hid]) / n;
        float var  = (red[0][64 + hid] + red[1][64 + hid] + red[2][64 + hid] + red[3][64 + hid]) / n
                     - mean * mean;
        float inv  = rsqrtf(var + EPS);
        float sc   = gamma[hid] * inv;
        stats[hid]      = sc;
        stats[64 + hid] = beta[hid] - mean * sc;
    }
}

__global__ __launch_bounds__(256) void normalize_k(float* __restrict__ out,
                                                   const float* __restrict__ stats) {
    const size_t N = (size_t)BB * TT * HID * HH * WW;
    size_t i = ((size_t)blockIdx.x * blockDim.x + threadIdx.x) * 4;
    size_t stride = (size_t)gridDim.x * blockDim.x * 4;
    for (; i < N; i += stride) {
        int ch = (int)((i >> 12) & (HID - 1));
        float sc = stats[ch], sh = stats[64 + ch];
        float4 v = *(float4*)(out + i);
        v.x = fmaf(v.x, sc, sh);
        v.y = fmaf(v.y, sc, sh);
        v.z = fmaf(v.z, sc, sh);
        v.w = fmaf(v.w, sc, sh);
        *(float4*)(out + i) = v;
    }
}

extern "C" void kernel_launch(void* const* d_in, const int* in_sizes, int n_in,
                              void* d_out, int out_size, void* d_ws, size_t ws_size,
                              hipStream_t stream) {
    const float* x     = (const float*)d_in[0];
    const float* w     = (const float*)d_in[1];
    const float* bias  = (const float*)d_in[2];
    const float* gamma = (const float*)d_in[3];
    const float* beta  = (const float*)d_in[4];
    float* out = (float*)d_out;
    char* wsb = (char*)d_ws;

    // d_ws is 512 MB (the harness poison fills 512 MB); total use: 59.4 MB.
    _Float16* xcl   = (_Float16*)(wsb);                    // 33,554,432 B
    _Float16* wpk   = (_Float16*)(wsb + 33554432);         //    442,368 B
    _Float16* hA    = (_Float16*)(wsb + 33996800);         //  4,194,304 B
    _Float16* hB    = (_Float16*)(wsb + 38191104);         //  4,194,304 B
    float* cA       = (float*)(wsb + 42385408);            //  8,388,608 B
    float* cB       = (float*)(wsb + 50774016);            //  8,388,608 B
    float* partial  = (float*)(wsb + 59162624);            //    262,144 B
    float* stats    = (float*)(wsb + 59424768);            //        512 B

    const int LDSZ = (6 * 66 * 104 + 4 * 66 * 104) * 2;    // 137,280 B

    x2h<<<dim3(64, 16, 8), 256, 0, stream>>>(x, xcl);
    pack_wh<<<864, 256, 0, stream>>>(w, wpk);

    static bool attr_set = false;
    if (!attr_set) {
        hipFuncSetAttribute(reinterpret_cast<const void*>(lstm_pair),
                            hipFuncAttributeMaxDynamicSharedMemorySize, LDSZ);
        attr_set = true;
    }

    _Float16* hin = hA;  _Float16* hout = hB;
    float* cin = cA;     float* cout = cB;
    for (int p = 0; p < 8; ++p) {
        lstm_pair<<<dim3(32, 8), 512, LDSZ, stream>>>(xcl, wpk, bias, hin, hout,
                                                      cin, cout, out, partial, 2 * p);
        _Float16* th = hin; hin = hout; hout = th;
        float* tc = cin; cin = cout; cout = tc;
    }
    finalize_stats<<<1, 512, 0, stream>>>(partial, stats, gamma, beta);
    normalize_k<<<8192, 256, 0, stream>>>(out, stats);
}

// Round 9
// 581.802 us; speedup vs baseline: 1.1822x; 1.1822x over previous
//
#include <hip/hip_runtime.h>

#define BB 8
#define TT 16
#define CIN 32
#define HID 64
#define HH 64
#define WW 64
#define EPS 1e-3f
#define NEG_SLOPE 0.01f

typedef short s16x8 __attribute__((ext_vector_type(8)));
typedef _Float16 hx8 __attribute__((ext_vector_type(8)));
typedef float fx4 __attribute__((ext_vector_type(4)));
typedef unsigned long long u64;

__device__ __forceinline__ float tanh_fast(float x) {
    x = fminf(fmaxf(x, -15.f), 15.f);
    float e = __expf(-2.f * x);
    return (1.f - e) / (1.f + e);
}

// x (NCHW fp32) -> xcl [b][t][y*64+x][32] f16
__global__ __launch_bounds__(256) void x2h(const float* __restrict__ x,
                                           _Float16* __restrict__ xcl) {
    __shared__ float s[32][65];
    int y = blockIdx.x, t = blockIdx.y, b = blockIdx.z;
    int tid = threadIdx.x;
    const float* src = x + (((size_t)(b * TT + t) * CIN) * HH + y) * WW;
#pragma unroll
    for (int k = 0; k < 8; ++k) {
        int idx = tid + k * 256;
        int c = idx >> 6, xx = idx & 63;
        s[c][xx] = src[(size_t)c * HH * WW + xx];
    }
    __syncthreads();
    int xx = tid >> 2, c0 = (tid & 3) * 8;
    _Float16 tmp[8];
#pragma unroll
    for (int j = 0; j < 8; ++j) tmp[j] = (_Float16)s[c0 + j][xx];
    _Float16* dst = xcl + (((size_t)(b * TT + t) * 4096) + y * 64 + xx) * 32 + c0;
    *(hx8*)dst = *(hx8*)tmp;
}

// w [256 oc][96 ch][3][3] fp32 -> wpk [tap(9)][kc(3)][kq(4)][n(256)][k7(8)] f16
__global__ __launch_bounds__(256) void pack_wh(const float* __restrict__ w,
                                               _Float16* __restrict__ wpk) {
    int idx = blockIdx.x * 256 + threadIdx.x;
    if (idx >= 256 * 864) return;
    int k7 = idx & 7;
    int j = idx >> 3;
    int n = j & 255;
    int kk = j >> 8;            // tap*12 + kc*4 + kq
    int tap = kk / 12;
    int r12 = kk % 12;
    int ks = (r12 >> 2) * 32 + (r12 & 3) * 8 + k7;
    int gate = (n >> 4) & 3;
    int hid  = (n >> 6) * 16 + (n & 15);
    int oc   = gate * 64 + hid;
    wpk[idx] = (_Float16)w[((size_t)oc * 96 + ks) * 9 + tap];
}

// Persistent fence-free ConvLSTM: all 16 steps, one launch.
// grid (32 r, 8 b) = 256 blocks = #CUs (all co-resident; 1 block/CU floor),
// 512 thr = 8 waves: u=w>>2 owns row yy=2r+u, w4=w&3 owns N-quadrant.
// State residency: c -> registers; own-row h -> LDS (epilogue writes it for
// the next step); ONLY halo h crosses blocks, via RELAXED agent-scope 64-bit
// atomics (per-access L1/L2 bypass -> coherent across XCDs with NO wbl2/inv
// fences; weights/xcl stay L2-hot; this is what r4's fence storm broke).
// Ordering: __syncthreads drains each wave's vmcnt (halo stores complete at
// the coherence point) before tid0's flag store; reader spins on flag, then
// loads. Bounded spin (~56 ms/step) converts any residency failure into a
// wrong answer instead of a dead container (r3 lesson).
// Halo global layout: [b][y][ch][pg] as u64 (4 consecutive px per chunk), so
// the epilogue publishes straight from registers (lane owns 4 px x 1 ch).
__global__ __launch_bounds__(512, 2) void lstm_all(
    const _Float16* __restrict__ xcl,
    const _Float16* __restrict__ wpk,
    const float* __restrict__ bias,
    u64* __restrict__ haloA,
    u64* __restrict__ haloB,
    float* __restrict__ out,
    float* __restrict__ partial,
    int* __restrict__ flags) {
    const int r = blockIdx.x, b = blockIdx.y;
    const int tid = threadIdx.x;
    const int lane15 = tid & 15;
    const int kq = (tid >> 4) & 3;
    const int w = tid >> 6;
    const int w4 = w & 3;
    const int u = w >> 2;
    const int yy = 2 * r + u;

    // 4 rows (2r-1 .. 2r+2) x 66 cols x 104 ch-stride (x ch0..31, h ch32..95)
    __shared__ __align__(16) unsigned short s_t[4 * 66 * 104];   // 54,912 B

    const int hid = w4 * 16 + lane15;
    const float bi = bias[hid], bff = bias[64 + hid];
    const float bo = bias[128 + hid], bg = bias[192 + hid];
    const int nbase = 4 * w4 * 16 + lane15;

    fx4 creg[4];
#pragma unroll
    for (int j = 0; j < 4; ++j) creg[j] = (fx4)0.f;
    float osum = 0.f, osum2 = 0.f;

    // zero ALL h slots once (incl. col 0/65 pad, which persists all steps:
    // staging only writes cols 1..64 of rows 0/3, epilogue cols 1..64 of 1/2)
    for (int i = tid; i < 4 * 66 * 8; i += 512) {
        int unit = i & 7, pix = i >> 3;
        *(s16x8*)(s_t + pix * 104 + 32 + unit * 8) = (s16x8)0;
    }

#pragma unroll 1
    for (int t = 0; t < TT; ++t) {
        // ---- wait for neighbors' h(t-1) ----
        if (t > 0) {
            if (tid < 2) {
                int nb = r + (tid ? 1 : -1);
                if (nb >= 0 && nb < 32) {
                    const int fid = b * 32 + nb;
                    int spins = 0;
                    while (__hip_atomic_load(&flags[fid], __ATOMIC_RELAXED,
                                             __HIP_MEMORY_SCOPE_AGENT) < t) {
                        __builtin_amdgcn_s_sleep(2);
                        if (++spins > (1 << 20)) break;
                    }
                }
            }
            __syncthreads();
        }

        // ---- stage x(t): 4 rows x 66 cols x 32ch from L2-hot xcl ----
        const short* xb_t = (const short*)xcl + (size_t)(b * TT + t) * 4096 * 32;
        for (int i = tid; i < 4 * 66 * 4; i += 512) {
            int unit = i & 3, pix = i >> 2;
            int col = pix % 66, ra = pix / 66;
            int iy = 2 * r - 1 + ra, ix = col - 1;
            s16x8 v = (s16x8)0;
            if (iy >= 0 && iy < 64 && ix >= 0 && ix < 64)
                v = *(const s16x8*)(xb_t + ((size_t)iy * 64 + ix) * 32 + unit * 8);
            *(s16x8*)(s_t + pix * 104 + unit * 8) = v;
        }
        // ---- stage halo h(t-1) rows (ra 0 and 3) via coherent loads ----
        if (t > 0) {
            const u64* hb = ((t - 1) & 1) ? haloB : haloA;
            for (int i = tid; i < 2 * 64 * 16; i += 512) {
                int pg = i & 15, ch = (i >> 4) & 63, side = i >> 10;
                int ra = side ? 3 : 0;
                int iy = side ? (2 * r + 2) : (2 * r - 1);
                u64 v = 0;
                if (iy >= 0 && iy < 64)
                    v = __hip_atomic_load(&hb[((size_t)(b * 64 + iy) * 64 + ch) * 16 + pg],
                                          __ATOMIC_RELAXED, __HIP_MEMORY_SCOPE_AGENT);
                union { u64 q; unsigned short s[4]; } uv; uv.q = v;
                int colb = 1 + pg * 4;
#pragma unroll
                for (int k = 0; k < 4; ++k)
                    s_t[(ra * 66 + colb + k) * 104 + 32 + ch] = uv.s[k];
            }
        }
        __syncthreads();

        // ---- taps: 9 x 3kc x {4 bf (L2) + 4 ds_b128 + 16 MFMA} ----
        // (t=0 reads the zeroed h slots: exact 0-contribution, single path)
        fx4 acc[4][4];
#pragma unroll
        for (int j = 0; j < 4; ++j)
#pragma unroll
            for (int g = 0; g < 4; ++g) acc[j][g] = (fx4)0.f;

#pragma unroll 1
        for (int tap = 0; tap < 9; ++tap) {
            const int ky = tap / 3, kx = tap % 3;
            const _Float16* wp = wpk + ((size_t)(tap * 12 + kq) * 256 + nbase) * 8;
            const unsigned short* abase = s_t + ((u + ky) * 66 + lane15 + kx) * 104 + kq * 8;
#pragma unroll
            for (int kc = 0; kc < 3; ++kc) {
                hx8 bf[4];
#pragma unroll
                for (int g = 0; g < 4; ++g)
                    bf[g] = *(const hx8*)(wp + (size_t)(kc * 4) * 256 * 8 + g * 16 * 8);
#pragma unroll
                for (int j = 0; j < 4; ++j) {
                    hx8 af = *(const hx8*)(abase + j * 16 * 104 + kc * 32);
#pragma unroll
                    for (int g = 0; g < 4; ++g)
                        acc[j][g] = __builtin_amdgcn_mfma_f32_16x16x32_f16(af, bf[g], acc[j][g], 0, 0, 0);
                }
            }
        }
        __syncthreads();   // taps done everywhere before epilogue rewrites LDS h

        // ---- epilogue: gates; c in regs; h -> LDS (next step) + halo pub ----
        u64* hbc = (t & 1) ? haloB : haloA;
#pragma unroll
        for (int j = 0; j < 4; ++j) {
            int px0 = j * 16 + kq * 4;
            float4 o4;
            union { u64 q; unsigned short s[4]; } hp;
#pragma unroll
            for (int r4 = 0; r4 < 4; ++r4) {
                float ci = acc[j][0][r4] + bi;
                float cf = acc[j][1][r4] + bff;
                float co = acc[j][2][r4] + bo;
                float cg_ = acc[j][3][r4] + bg;
                float c_old = creg[j][r4];
                float si = 1.f / (1.f + __expf(-ci));
                float sf = 1.f / (1.f + __expf(-cf));
                float so = 1.f / (1.f + __expf(-co));
                float c_new = sf * c_old + si * tanh_fast(cg_);
                float h = so * tanh_fast(c_new);
                creg[j][r4] = c_new;
                _Float16 hh = (_Float16)h;
                union { _Float16 f; unsigned short s; } hc; hc.f = hh;
                hp.s[r4] = hc.s;
                if (t < TT - 1)
                    s_t[((1 + u) * 66 + 1 + px0 + r4) * 104 + 32 + hid] = hc.s;
                float ov = (h >= 0.f) ? h : NEG_SLOPE * h;
                (&o4.x)[r4] = ov;
                osum += ov;
                osum2 += ov * ov;
            }
            if (t < TT - 1)
                __hip_atomic_store(&hbc[((size_t)(b * 64 + yy) * 64 + hid) * 16 + (j * 4 + kq)],
                                   hp.q, __ATOMIC_RELAXED, __HIP_MEMORY_SCOPE_AGENT);
            *(float4*)(out + (((size_t)(b * TT + t) * 64 + hid) * 64 + yy) * 64 + px0) = o4;
        }

        // ---- publish: barrier drains every wave's halo stores, then flag ----
        if (t < TT - 1) {
            __syncthreads();
            if (tid == 0)
                __hip_atomic_store(&flags[b * 32 + r], t + 1,
                                   __ATOMIC_RELAXED, __HIP_MEMORY_SCOPE_AGENT);
        }
    }

    osum  += __shfl_xor(osum, 16);  osum  += __shfl_xor(osum, 32);
    osum2 += __shfl_xor(osum2, 16); osum2 += __shfl_xor(osum2, 32);
    if (kq == 0) {
        int slot = b * 64 + yy;
        partial[slot * 128 + hid] = osum;
        partial[slot * 128 + 64 + hid] = osum2;
    }
}

__global__ __launch_bounds__(512) void finalize_stats(const float* __restrict__ partial,
                                                      float* __restrict__ stats,
                                                      const float* __restrict__ gamma,
                                                      const float* __restrict__ beta) {
    int idx = threadIdx.x & 127;
    int seg = threadIdx.x >> 7;       // 0..3, each sums 128 of 512 rows
    float s = 0.f;
    for (int k = seg * 128; k < seg * 128 + 128; ++k) s += partial[k * 128 + idx];
    __shared__ float red[4][128];
    red[seg][idx] = s;
    __syncthreads();
    if (threadIdx.x < 64) {
        int hid = threadIdx.x;
        const float n = (float)((size_t)BB * TT * HH * WW);
        float mean = (red[0][hid] + red[1][hid] + red[2][hid] + red[3][hid]) / n;
        float var  = (red[0][64 + hid] + red[1][64 + hid] + red[2][64 + hid] + red[3][64 + hid]) / n
                     - mean * mean;
        float inv  = rsqrtf(var + EPS);
        float sc   = gamma[hid] * inv;
        stats[hid]      = sc;
        stats[64 + hid] = beta[hid] - mean * sc;
    }
}

__global__ __launch_bounds__(256) void normalize_k(float* __restrict__ out,
                                                   const float* __restrict__ stats) {
    const size_t N = (size_t)BB * TT * HID * HH * WW;
    size_t i = ((size_t)blockIdx.x * blockDim.x + threadIdx.x) * 4;
    size_t stride = (size_t)gridDim.x * blockDim.x * 4;
    for (; i < N; i += stride) {
        int ch = (int)((i >> 12) & (HID - 1));
        float sc = stats[ch], sh = stats[64 + ch];
        float4 v = *(float4*)(out + i);
        v.x = fmaf(v.x, sc, sh);
        v.y = fmaf(v.y, sc, sh);
        v.z = fmaf(v.z, sc, sh);
        v.w = fmaf(v.w, sc, sh);
        *(float4*)(out + i) = v;
    }
}

extern "C" void kernel_launch(void* const* d_in, const int* in_sizes, int n_in,
                              void* d_out, int out_size, void* d_ws, size_t ws_size,
                              hipStream_t stream) {
    const float* x     = (const float*)d_in[0];
    const float* w     = (const float*)d_in[1];
    const float* bias  = (const float*)d_in[2];
    const float* gamma = (const float*)d_in[3];
    const float* beta  = (const float*)d_in[4];
    float* out = (float*)d_out;
    char* wsb = (char*)d_ws;

    // Total workspace use: 42,649,088 B (d_ws is 512 MB).
    _Float16* xcl  = (_Float16*)(wsb);                    // 33,554,432 B
    _Float16* wpk  = (_Float16*)(wsb + 33554432);         //    442,368 B
    u64* haloA     = (u64*)(wsb + 33996800);              //  4,194,304 B
    u64* haloB     = (u64*)(wsb + 38191104);              //  4,194,304 B
    float* partial = (float*)(wsb + 42385408);            //    262,144 B
    float* stats   = (float*)(wsb + 42647552);            //        512 B
    int*   flags   = (int*)(wsb + 42648064);              //      1,024 B

    hipMemsetAsync(flags, 0, 1024, stream);

    x2h<<<dim3(64, 16, 8), 256, 0, stream>>>(x, xcl);
    pack_wh<<<864, 256, 0, stream>>>(w, wpk);

    lstm_all<<<dim3(32, 8), 512, 0, stream>>>(xcl, wpk, bias, haloA, haloB,
                                              out, partial, flags);

    finalize_stats<<<1, 512, 0, stream>>>(partial, stats, gamma, beta);
    normalize_k<<<8192, 256, 0, stream>>>(out, stats);
}